// Round 1
// baseline (571.121 us; speedup 1.0000x reference)
//
#include <hip/hip_runtime.h>
#include <hip/hip_bf16.h>
#include <stdint.h>

// ---------- types ----------
typedef __attribute__((ext_vector_type(8)))  short bf16x8;   // MFMA A/B operand (4 VGPR)
typedef __attribute__((ext_vector_type(4)))  float f32x4;    // MFMA C/D operand
typedef __attribute__((ext_vector_type(4)))  float float4v;
typedef __attribute__((ext_vector_type(8)))  unsigned short u16x8;

#define MFMA16(a, b, c) __builtin_amdgcn_mfma_f32_16x16x32_bf16((a), (b), (c), 0, 0, 0)

// fp32 -> bf16 RNE (no NaN handling needed; inputs are finite gaussians)
__device__ __forceinline__ unsigned short f2bf(float f) {
    unsigned int u = __builtin_bit_cast(unsigned int, f);
    u = (u + 0x7fffu + ((u >> 16) & 1u)) >> 16;
    return (unsigned short)u;
}

// async global->LDS, 16B per lane. lds ptr must be wave-uniform; lane i lands at lds + i*16.
__device__ __forceinline__ void gload_lds16(const void* g, void* l) {
    __builtin_amdgcn_global_load_lds(
        (const __attribute__((address_space(1))) void*)g,
        (__attribute__((address_space(3))) void*)l,
        16, 0, 0);
}

// ---------- kernel 1: fp32 -> bf16 convert (vectorized, grid-stride) ----------
__global__ void cvt_f32_bf16(const float* __restrict__ in, unsigned short* __restrict__ out, long n) {
    long i = ((long)blockIdx.x * blockDim.x + threadIdx.x) * 8;
    long stride = (long)gridDim.x * blockDim.x * 8;
    for (; i < n; i += stride) {
        float4v v0 = *(const float4v*)(in + i);
        float4v v1 = *(const float4v*)(in + i + 4);
        u16x8 o;
        o[0] = f2bf(v0[0]); o[1] = f2bf(v0[1]); o[2] = f2bf(v0[2]); o[3] = f2bf(v0[3]);
        o[4] = f2bf(v1[0]); o[5] = f2bf(v1[1]); o[6] = f2bf(v1[2]); o[7] = f2bf(v1[3]);
        *(u16x8*)(out + i) = o;
    }
}

// ---------- kernel 2: z = H(bf16) @ VT(bf16)^T  [16384x2048] ----------
// m97-style structure: 128x128 tile, BK=64, 4 waves, global_load_lds width 16, 2 barriers/K-step.
#define G1_BM 128
#define G1_BN 128
#define G1_BK 64
#define G1_K  4096
#define G1_N  2048

__global__ __launch_bounds__(256) void gemm1(const unsigned short* __restrict__ A,  // [16384][4096] bf16
                                             const unsigned short* __restrict__ B,  // [2048][4096] bf16
                                             unsigned short* __restrict__ Z) {      // [16384][2048] bf16
    __shared__ __align__(16) unsigned short lA[G1_BM * G1_BK];
    __shared__ __align__(16) unsigned short lB[G1_BN * G1_BK];

    const int tid  = threadIdx.x;
    const int lane = tid & 63;
    const int wid  = tid >> 6;
    const int bx   = blockIdx.x & 15;        // n-tile (16 of them) -> consecutive blocks share A panel
    const int by   = blockIdx.x >> 4;        // m-tile (128)
    const long m0  = (long)by * G1_BM;
    const long n0  = (long)bx * G1_BN;
    const int wr   = wid >> 1;               // 0..1
    const int wc   = wid & 1;                // 0..1

    f32x4 acc[4][4] = {};

    // staging geometry: one wave issue covers 8 rows x 128B; 4 issues/wave -> 128 rows
    const int srow = lane >> 3;              // 0..7
    const int scol = (lane & 7) * 8;         // bf16 elems, 16B granules
    const unsigned short* aBase = A + m0 * G1_K;
    const unsigned short* bBase = B + n0 * G1_K;

    for (int k0 = 0; k0 < G1_K; k0 += G1_BK) {
        __syncthreads();   // previous tile's LDS reads done
        #pragma unroll
        for (int j = 0; j < 4; ++j) {
            const int rbase = j * 32 + wid * 8;                  // wave-uniform
            const long r = rbase + srow;
            gload_lds16(aBase + r * G1_K + k0 + scol, &lA[rbase * G1_BK]);
            gload_lds16(bBase + r * G1_K + k0 + scol, &lB[rbase * G1_BK]);
        }
        __syncthreads();   // staging complete (compiler drains vmcnt here)

        #pragma unroll
        for (int kk = 0; kk < G1_BK; kk += 32) {
            bf16x8 af[4], bfr[4];
            const int kofs = kk + ((lane >> 4) << 3);
            #pragma unroll
            for (int mi = 0; mi < 4; ++mi)
                af[mi] = *(const bf16x8*)&lA[(wr * 64 + mi * 16 + (lane & 15)) * G1_BK + kofs];
            #pragma unroll
            for (int ni = 0; ni < 4; ++ni)
                bfr[ni] = *(const bf16x8*)&lB[(wc * 64 + ni * 16 + (lane & 15)) * G1_BK + kofs];
            #pragma unroll
            for (int mi = 0; mi < 4; ++mi)
                #pragma unroll
                for (int ni = 0; ni < 4; ++ni)
                    acc[mi][ni] = MFMA16(af[mi], bfr[ni], acc[mi][ni]);
        }
    }

    // epilogue: C/D layout col = lane&15, row = (lane>>4)*4 + j  -> store z as bf16
    const int rq = (lane >> 4) << 2;
    const int cq = lane & 15;
    #pragma unroll
    for (int mi = 0; mi < 4; ++mi) {
        #pragma unroll
        for (int ni = 0; ni < 4; ++ni) {
            const long mb = m0 + wr * 64 + mi * 16 + rq;
            const long nb = n0 + wc * 64 + ni * 16 + cq;
            #pragma unroll
            for (int j = 0; j < 4; ++j)
                Z[(mb + j) * (long)G1_N + nb] = f2bf(acc[mi][ni][j]);
        }
    }
}

// ---------- kernel 3: grouped up-projection out[m, g*128+d] = sum_r z[m, g*64+r] * U[g,d,r] ----------
// block = 64 rows x 1 group (128 cols); 4 waves each own 16 rows; K=64 -> 2 MFMA per n-fragment.
#define U_PAD 80   // 160B row stride: 4-way bank conflict instead of 16-way

__global__ __launch_bounds__(256) void gemm2(const unsigned short* __restrict__ Z,  // [16384][2048] bf16
                                             const float* __restrict__ U,           // [32][128][64] f32
                                             float* __restrict__ out) {             // [16384][4096] f32
    __shared__ __align__(16) unsigned short lU[128 * U_PAD];

    const int tid  = threadIdx.x;
    const int lane = tid & 63;
    const int wid  = tid >> 6;
    const int g    = blockIdx.x & 31;
    const long m0  = (long)(blockIdx.x >> 5) * 64;

    // stage U[g] (128x64 fp32) -> LDS bf16, padded rows
    const float* ug = U + (long)g * (128 * 64);
    for (int i = tid; i < (128 * 64) / 4; i += 256) {
        const int r = i >> 4;            // (i*4)/64
        const int c = (i << 2) & 63;     // (i*4)%64
        float4v v = *(const float4v*)(ug + i * 4);
        unsigned short* d = &lU[r * U_PAD + c];
        d[0] = f2bf(v[0]); d[1] = f2bf(v[1]); d[2] = f2bf(v[2]); d[3] = f2bf(v[3]);
    }
    __syncthreads();

    // A fragments from z (global, bf16): row = m0 + wid*16 + (lane&15), k = kk*32 + (lane>>4)*8
    const long mrow = m0 + wid * 16 + (lane & 15);
    const unsigned short* zrow = Z + mrow * (long)G1_N + g * 64 + ((lane >> 4) << 3);
    const bf16x8 a0 = *(const bf16x8*)(zrow);
    const bf16x8 a1 = *(const bf16x8*)(zrow + 32);

    f32x4 acc[8] = {};
    const int blds = (lane & 15);
    const int kofs = (lane >> 4) << 3;
    #pragma unroll
    for (int ni = 0; ni < 8; ++ni) {
        const bf16x8 b0 = *(const bf16x8*)&lU[(ni * 16 + blds) * U_PAD + kofs];
        const bf16x8 b1 = *(const bf16x8*)&lU[(ni * 16 + blds) * U_PAD + 32 + kofs];
        acc[ni] = MFMA16(a0, b0, acc[ni]);
        acc[ni] = MFMA16(a1, b1, acc[ni]);
    }

    const long mb = m0 + wid * 16 + ((lane >> 4) << 2);
    const long cb = (long)g * 128 + (lane & 15);
    #pragma unroll
    for (int ni = 0; ni < 8; ++ni)
        #pragma unroll
        for (int j = 0; j < 4; ++j)
            out[(mb + j) * 4096L + cb + ni * 16] = acc[ni][j];
}

// ---------- launch ----------
extern "C" void kernel_launch(void* const* d_in, const int* in_sizes, int n_in,
                              void* d_out, int out_size, void* d_ws, size_t ws_size,
                              hipStream_t stream) {
    const float* hs = (const float*)d_in[0];   // [4,4096,4096]  = 67108864
    const float* vt = (const float*)d_in[1];   // [2048,4096]    =  8388608
    const float* uw = (const float*)d_in[2];   // [32,128,64]    =   262144
    float* out = (float*)d_out;                // [4,4096,4096]

    unsigned short* hs_bf = (unsigned short*)d_ws;            // 67108864 bf16
    unsigned short* vt_bf = hs_bf + 67108864L;                //  8388608 bf16
    unsigned short* z_bf  = vt_bf + 8388608L;                 // 33554432 bf16

    cvt_f32_bf16<<<2048, 256, 0, stream>>>(hs, hs_bf, 67108864L);
    cvt_f32_bf16<<<512, 256, 0, stream>>>(vt, vt_bf, 8388608L);

    // GEMM1: grid = (16384/128) * (2048/128) = 128*16 = 2048 blocks
    gemm1<<<2048, 256, 0, stream>>>(hs_bf, vt_bf, z_bf);

    // GEMM2: grid = (16384/64) * 32 groups = 8192 blocks
    gemm2<<<8192, 256, 0, stream>>>(z_bf, uw, out);
}

// Round 2
// 377.008 us; speedup vs baseline: 1.5149x; 1.5149x over previous
//
#include <hip/hip_runtime.h>
#include <hip/hip_bf16.h>
#include <stdint.h>

// ---------- types ----------
typedef __attribute__((ext_vector_type(8)))  short bf16x8;
typedef __attribute__((ext_vector_type(4)))  float f32x4;
typedef __attribute__((ext_vector_type(4)))  float float4v;
typedef __attribute__((ext_vector_type(8)))  unsigned short u16x8;

#define MFMA16(a,b,c) __builtin_amdgcn_mfma_f32_16x16x32_bf16((a),(b),(c),0,0,0)

__device__ __forceinline__ unsigned short f2bf(float f) {
    unsigned int u = __builtin_bit_cast(unsigned int, f);
    u = (u + 0x7fffu + ((u >> 16) & 1u)) >> 16;
    return (unsigned short)u;
}

__device__ __forceinline__ void gload_lds16(const void* g, void* l) {
    __builtin_amdgcn_global_load_lds(
        (const __attribute__((address_space(1))) void*)g,
        (__attribute__((address_space(3))) void*)l, 16, 0, 0);
}

template<int N> __device__ __forceinline__ void waitvm() {}  // N<0: no wait
template<> __device__ __forceinline__ void waitvm<6>() { asm volatile("s_waitcnt vmcnt(6)" ::: "memory"); }
template<> __device__ __forceinline__ void waitvm<4>() { asm volatile("s_waitcnt vmcnt(4)" ::: "memory"); }
template<> __device__ __forceinline__ void waitvm<2>() { asm volatile("s_waitcnt vmcnt(2)" ::: "memory"); }
template<> __device__ __forceinline__ void waitvm<0>() { asm volatile("s_waitcnt vmcnt(0)" ::: "memory"); }

// ---------- fp32 -> bf16 convert ----------
__global__ void cvt_f32_bf16(const float* __restrict__ in, unsigned short* __restrict__ out, long n) {
    long i = ((long)blockIdx.x * blockDim.x + threadIdx.x) * 8;
    long stride = (long)gridDim.x * blockDim.x * 8;
    for (; i < n; i += stride) {
        float4v v0 = *(const float4v*)(in + i);
        float4v v1 = *(const float4v*)(in + i + 4);
        u16x8 o;
        o[0] = f2bf(v0[0]); o[1] = f2bf(v0[1]); o[2] = f2bf(v0[2]); o[3] = f2bf(v0[3]);
        o[4] = f2bf(v1[0]); o[5] = f2bf(v1[1]); o[6] = f2bf(v1[2]); o[7] = f2bf(v1[3]);
        *(u16x8*)(out + i) = o;
    }
}

// ---------- GEMM1: 256x256 tile, BK=64, 8-phase counted-vmcnt schedule ----------
// M=16384, N=2048, K=4096. 8 waves (2M x 4N), per-wave output 128x64.
// LDS: 2 buffers x (A 256x64 + B 256x64) bf16 = 128 KiB.
// Swizzle: LDS phys granule = logical granule ^ (row&7); applied as inverse-swizzled
// GLOBAL source on stage (linear gload_lds dest) + swizzled ds_read address.
// Half-tile regions: Ah(h) = rows {h*64..h*64+63} U {128+h*64..}; Bh(h) = rows with bit5==h.
// Phase p consumes a half issued 4 phases earlier; waits vmcnt(6)@p0, (6)@p1, (4)@p3.

// stage: l=0/1, h=0/1; global row A = q + l*128 + h*64 ; B = rB0 + l*128 + h*32
#define STAGE_A(nA_, k0n, h, l) \
    gload_lds16(pA + ((l)*128 + (h)*64) * 4096L + (k0n), (nA_) + dA0 + ((l)*128 + (h)*64) * 64)
#define STAGE_B(nB_, k0n, h, l) \
    gload_lds16(pB + ((l)*128 + (h)*32) * 4096L + (k0n), (nB_) + dB0 + ((l)*128 + (h)*32) * 64)

// swizzled fragment reads: row = base + lan15 (base%8==0 -> row&7 == lane&7)
#define LDA(sA_, QM) do { _Pragma("unroll") for (int mi = 0; mi < 4; ++mi) { \
    a[mi][0] = *(const bf16x8*)((sA_) + ((wr*128 + (QM)*64 + mi*16 + lan15) << 6) + g0); \
    a[mi][1] = *(const bf16x8*)((sA_) + ((wr*128 + (QM)*64 + mi*16 + lan15) << 6) + (g0 ^ 32)); } } while (0)
#define LDB(sB_, QN) do { _Pragma("unroll") for (int ni = 0; ni < 2; ++ni) { \
    b[ni][0] = *(const bf16x8*)((sB_) + ((wc*64 + (QN)*32 + ni*16 + lan15) << 6) + g0); \
    b[ni][1] = *(const bf16x8*)((sB_) + ((wc*64 + (QN)*32 + ni*16 + lan15) << 6) + (g0 ^ 32)); } } while (0)

#define DOMFMA(QM, QN) do { __builtin_amdgcn_s_setprio(1); \
    _Pragma("unroll") for (int mi = 0; mi < 4; ++mi) \
      _Pragma("unroll") for (int ni = 0; ni < 2; ++ni) { \
        acc[(QM)*4+mi][(QN)*2+ni] = MFMA16(a[mi][0], b[ni][0], acc[(QM)*4+mi][(QN)*2+ni]); \
        acc[(QM)*4+mi][(QN)*2+ni] = MFMA16(a[mi][1], b[ni][1], acc[(QM)*4+mi][(QN)*2+ni]); } \
    __builtin_amdgcn_s_setprio(0); } while (0)

#define BAR1() do { __builtin_amdgcn_s_barrier(); \
    asm volatile("s_waitcnt lgkmcnt(0)" ::: "memory"); \
    __builtin_amdgcn_sched_barrier(0); } while (0)
#define BAR2() do { __builtin_amdgcn_s_barrier(); \
    __builtin_amdgcn_sched_barrier(0); } while (0)

#define KTILE(sA_, sB_, nA_, nB_, k0n, DOSTAGE, V0, V1, V3) do { \
    /* phase 0: Q(0,0) needs Ah0,Bh0 */ \
    LDA(sA_, 0); LDB(sB_, 0); \
    if (DOSTAGE) { STAGE_A(nA_, k0n, 0, 0); STAGE_A(nA_, k0n, 0, 1); \
                   STAGE_B(nB_, k0n, 0, 0); STAGE_B(nB_, k0n, 0, 1); } \
    BAR1(); DOMFMA(0, 0); waitvm<V0>(); BAR2(); \
    /* phase 1: Q(0,1) needs Bh1 (A reused) */ \
    LDB(sB_, 1); \
    if (DOSTAGE) { STAGE_B(nB_, k0n, 1, 0); STAGE_B(nB_, k0n, 1, 1); } \
    BAR1(); DOMFMA(0, 1); waitvm<V1>(); BAR2(); \
    /* phase 2: Q(1,1) needs Ah1 (B reused) */ \
    LDA(sA_, 1); \
    if (DOSTAGE) { STAGE_A(nA_, k0n, 1, 0); STAGE_A(nA_, k0n, 1, 1); } \
    BAR1(); DOMFMA(1, 1); BAR2(); \
    /* phase 3: Q(1,0) re-reads Bh0 of current tile */ \
    LDB(sB_, 0); \
    BAR1(); DOMFMA(1, 0); waitvm<V3>(); BAR2(); \
} while (0)

__global__ __launch_bounds__(512, 2) void gemm1_8ph(const unsigned short* __restrict__ A,  // [16384][4096]
                                                    const unsigned short* __restrict__ B,  // [2048][4096]
                                                    unsigned short* __restrict__ Z) {      // [16384][2048]
    __shared__ __align__(16) unsigned short lds[65536];   // 128 KiB: 2 bufs x (A 16384 + B 16384)

    const int tid   = threadIdx.x;
    const int lane  = tid & 63;
    const int wid   = tid >> 6;
    const int wr    = wid >> 2;          // 0..1
    const int wc    = wid & 3;           // 0..3
    const int lan15 = lane & 15;
    const int g0    = (((lane >> 4) ^ (lane & 7)) << 3);  // phys-granule elem offset, ks=0

    // XCD swizzle: n-tile = bid&7 (one n-panel per XCD L2), m-tile = bid>>3
    const int  bid = blockIdx.x;
    const long m0  = (long)(bid >> 3) * 256;
    const long n0  = (long)(bid & 7) * 256;

    // stage addressing (per-thread invariants)
    const int q     = tid >> 3;                               // 0..63
    const int granA = (((tid & 7) ^ (q & 7)) << 3);           // inverse-swizzled global col (elems)
    const unsigned short* pA = A + (m0 + q) * 4096L + granA;
    const int rB0   = (q & 31) + ((q >> 5) << 6);
    const unsigned short* pB = B + (n0 + rB0) * 4096L + granA;
    const int dA0   = (wid * 8) * 64;                               // LDS elem base, l=h=0
    const int dB0   = ((wid & 3) * 8 + ((wid >> 2) << 6)) * 64;

    f32x4 acc[8][4] = {};
    bf16x8 a[4][2], b[2][2];

    unsigned short* buf0 = lds;
    unsigned short* buf1 = lds + 32768;

    // prologue: stage tile 0 (issue order Ah0, Bh0, Bh1, Ah1); keep last 2 halves in flight
    STAGE_A(buf0, 0, 0, 0); STAGE_A(buf0, 0, 0, 1);
    STAGE_B(buf0 + 16384, 0, 0, 0); STAGE_B(buf0 + 16384, 0, 0, 1);
    STAGE_B(buf0 + 16384, 0, 1, 0); STAGE_B(buf0 + 16384, 0, 1, 1);
    STAGE_A(buf0, 0, 1, 0); STAGE_A(buf0, 0, 1, 1);
    waitvm<4>();
    BAR2();

    for (int t = 0; t < 63; ++t) {
        unsigned short* cb = (t & 1) ? buf1 : buf0;
        unsigned short* nb = (t & 1) ? buf0 : buf1;
        KTILE(cb, cb + 16384, nb, nb + 16384, (t + 1) * 64, true, 6, 6, 4);
    }
    // last tile (t=63, parity 1): no staging; drain 2 -> 0
    KTILE(buf1, buf1 + 16384, buf0, buf0 + 16384, 0, false, 2, 0, -1);

    // epilogue: C/D col = lane&15 (n), row = (lane>>4)*4+j (m)
    const int rq = (lane >> 4) << 2;
    #pragma unroll
    for (int mi = 0; mi < 8; ++mi) {
        #pragma unroll
        for (int ni = 0; ni < 4; ++ni) {
            const long mb = m0 + wr * 128 + mi * 16 + rq;
            const long nb2 = n0 + wc * 64 + ni * 16 + lan15;
            #pragma unroll
            for (int j = 0; j < 4; ++j)
                Z[(mb + j) * 2048L + nb2] = f2bf(acc[mi][ni][j]);
        }
    }
}

// ---------- GEMM2: grouped up-projection (unchanged from round 1) ----------
#define U_PAD 80

__global__ __launch_bounds__(256) void gemm2(const unsigned short* __restrict__ Z,  // [16384][2048] bf16
                                             const float* __restrict__ U,           // [32][128][64] f32
                                             float* __restrict__ out) {             // [16384][4096] f32
    __shared__ __align__(16) unsigned short lU[128 * U_PAD];

    const int tid  = threadIdx.x;
    const int lane = tid & 63;
    const int wid  = tid >> 6;
    const int g    = blockIdx.x & 31;
    const long m0  = (long)(blockIdx.x >> 5) * 64;

    const float* ug = U + (long)g * (128 * 64);
    for (int i = tid; i < (128 * 64) / 4; i += 256) {
        const int r = i >> 4;
        const int c = (i << 2) & 63;
        float4v v = *(const float4v*)(ug + i * 4);
        unsigned short* d = &lU[r * U_PAD + c];
        d[0] = f2bf(v[0]); d[1] = f2bf(v[1]); d[2] = f2bf(v[2]); d[3] = f2bf(v[3]);
    }
    __syncthreads();

    const long mrow = m0 + wid * 16 + (lane & 15);
    const unsigned short* zrow = Z + mrow * 2048L + g * 64 + ((lane >> 4) << 3);
    const bf16x8 a0 = *(const bf16x8*)(zrow);
    const bf16x8 a1 = *(const bf16x8*)(zrow + 32);

    f32x4 acc[8] = {};
    const int blds = (lane & 15);
    const int kofs = (lane >> 4) << 3;
    #pragma unroll
    for (int ni = 0; ni < 8; ++ni) {
        const bf16x8 b0 = *(const bf16x8*)&lU[(ni * 16 + blds) * U_PAD + kofs];
        const bf16x8 b1 = *(const bf16x8*)&lU[(ni * 16 + blds) * U_PAD + 32 + kofs];
        acc[ni] = MFMA16(a0, b0, acc[ni]);
        acc[ni] = MFMA16(a1, b1, acc[ni]);
    }

    const long mb = m0 + wid * 16 + ((lane >> 4) << 2);
    const long cb = (long)g * 128 + (lane & 15);
    #pragma unroll
    for (int ni = 0; ni < 8; ++ni)
        #pragma unroll
        for (int j = 0; j < 4; ++j)
            out[(mb + j) * 4096L + cb + ni * 16] = acc[ni][j];
}

// ---------- launch ----------
extern "C" void kernel_launch(void* const* d_in, const int* in_sizes, int n_in,
                              void* d_out, int out_size, void* d_ws, size_t ws_size,
                              hipStream_t stream) {
    const float* hs = (const float*)d_in[0];   // [4,4096,4096]
    const float* vt = (const float*)d_in[1];   // [2048,4096]
    const float* uw = (const float*)d_in[2];   // [32,128,64]
    float* out = (float*)d_out;

    unsigned short* hs_bf = (unsigned short*)d_ws;
    unsigned short* vt_bf = hs_bf + 67108864L;
    unsigned short* z_bf  = vt_bf + 8388608L;

    cvt_f32_bf16<<<2048, 256, 0, stream>>>(hs, hs_bf, 67108864L);
    cvt_f32_bf16<<<512, 256, 0, stream>>>(vt, vt_bf, 8388608L);

    // GEMM1: (16384/256) x (2048/256) = 64 x 8 = 512 blocks, 512 threads
    gemm1_8ph<<<512, 512, 0, stream>>>(hs_bf, vt_bf, z_bf);

    // GEMM2: (16384/64) x 32 groups = 8192 blocks
    gemm2<<<8192, 256, 0, stream>>>(z_bf, uw, out);
}